// Round 3
// baseline (267.391 us; speedup 1.0000x reference)
//
#include <hip/hip_runtime.h>

#define NB 32
#define NN 256
#define DD 64
#define SROW 68          // LDS row stride in floats: 17 float4s -> conflict-free b128
#define FMAXV 3.402823466e+38f

// R9: ONE regular dispatch. R7 (grid.sync) and R8 (__threadfence tail) both
// proved device-scope sync costs 25-70us on 8-XCD gfx950; kernel boundaries
// are the only cheap cross-block barrier, but each dispatch costs ~14.5us of
// launch overhead (calibrated: R6 = 40 fill + 8 kernels + 5*14.5 = 120.5;
// R8 = 40 + 69 + 3*14.5 = 151.7). So: one block per batch (32 blocks x 1024
// threads), ALL cross-node reductions intra-block via __syncthreads. No ws.
// VALU floor: 4096 FMA/thread -> ~14us on 32 CUs; LDS b128 h-reads (stride
// 68) fit underneath. Predicted dur ~= 40 + 16 + 2*14.5 ~= 85-95us.
//
// Thread org: 16 waves. w&7 -> dim-slice d0=8*(w&7); w>>3 -> node-half
// (2 node-groups of 64). tj max/min and pooling: fold 2 groups in-reg,
// 64-lane butterfly, halves combined via 1KB LDS partials.

__global__ __launch_bounds__(1024) void k_all(
    const float* __restrict__ x,
    const float* __restrict__ W1,  const float* __restrict__ b1,
    const float* __restrict__ g1,  const float* __restrict__ beta1,
    const float* __restrict__ We1, const float* __restrict__ be1,
    const float* __restrict__ ge1, const float* __restrict__ bte1,
    const float* __restrict__ We2, const float* __restrict__ be2,
    const float* __restrict__ ge2, const float* __restrict__ bte2,
    const float* __restrict__ Wg1, const float* __restrict__ bg1,
    const float* __restrict__ Wg2, const float* __restrict__ bg2,
    float* __restrict__ out)
{
    __shared__ __align__(16) float Hs[NN * SROW];   // 69,632 B
    __shared__ float PTmax[2 * DD], PTmin[2 * DD];  // per-half tj partials
    __shared__ float PS[2 * DD], PM[2 * DD];        // per-half pool partials
    __shared__ float xg[2 * DD], hid[DD];

    const int b    = blockIdx.x;
    const int l    = threadIdx.x & 63;                                 // node lane
    const int w    = __builtin_amdgcn_readfirstlane(threadIdx.x >> 6); // wave 0..15 (SGPR)
    const int dw   = w & 7;
    const int half = w >> 3;
    const int d0   = dw * 8;        // wave's 8-dim slice
    const int c0   = half * 2;      // first of this wave's 2 node-groups

    // ================= layer 1: h1 -> Hs =================
#pragma unroll
    for (int cc = 0; cc < 2; ++cc) {
        const int n = (c0 + cc) * 64 + l;
        float4 xv = *(const float4*)(x + ((size_t)b * NN + n) * 4);
        float a[8];
#pragma unroll
        for (int j = 0; j < 8; ++j) a[j] = b1[d0 + j];
#pragma unroll
        for (int j = 0; j < 8; ++j) a[j] = fmaf(xv.x, W1[0 * DD + d0 + j], a[j]);
#pragma unroll
        for (int j = 0; j < 8; ++j) a[j] = fmaf(xv.y, W1[1 * DD + d0 + j], a[j]);
#pragma unroll
        for (int j = 0; j < 8; ++j) a[j] = fmaf(xv.z, W1[2 * DD + d0 + j], a[j]);
#pragma unroll
        for (int j = 0; j < 8; ++j) a[j] = fmaf(xv.w, W1[3 * DD + d0 + j], a[j]);
        float* o = Hs + (size_t)n * SROW + d0;
        float h[8];
#pragma unroll
        for (int j = 0; j < 8; ++j) h[j] = g1[d0 + j] * fmaxf(a[j], 0.f) + beta1[d0 + j];
        *(float4*)(o)     = make_float4(h[0], h[1], h[2], h[3]);
        *(float4*)(o + 4) = make_float4(h[4], h[5], h[6], h[7]);
    }
    __syncthreads();

    // ============ conv1: matvec + tj reduce + epilogue -> Hs ============
    float ti[2][8];
    {
        float tj[2][8];
#pragma unroll
        for (int cc = 0; cc < 2; ++cc)
#pragma unroll
            for (int j = 0; j < 8; ++j) { ti[cc][j] = 0.f; tj[cc][j] = 0.f; }
#pragma unroll
        for (int cc = 0; cc < 2; ++cc) {
            const float* hrow = Hs + (size_t)((c0 + cc) * 64 + l) * SROW;
#pragma unroll
            for (int k4 = 0; k4 < 16; ++k4) {
                float4 hv = *(const float4*)(hrow + k4 * 4);
                const float hk[4] = {hv.x, hv.y, hv.z, hv.w};
#pragma unroll
                for (int kk = 0; kk < 4; ++kk) {
                    const int k = k4 * 4 + kk;
                    const float* wi = We1 + k * DD + d0;          // wave-uniform -> s_load
                    const float* wj = We1 + (DD + k) * DD + d0;   // wave-uniform -> s_load
#pragma unroll
                    for (int j = 0; j < 8; ++j) {
                        ti[cc][j] = fmaf(hk[kk], wi[j], ti[cc][j]);
                        tj[cc][j] = fmaf(hk[kk], wj[j], tj[cc][j]);
                    }
                }
            }
        }
        // tj max/min over this half's 128 nodes: fold groups, 64-lane butterfly
        float mx[8], mn[8];
#pragma unroll
        for (int j = 0; j < 8; ++j) {
            mx[j] = fmaxf(tj[0][j], tj[1][j]);
            mn[j] = fminf(tj[0][j], tj[1][j]);
        }
#pragma unroll
        for (int m = 1; m < 64; m <<= 1) {
#pragma unroll
            for (int j = 0; j < 8; ++j) {
                mx[j] = fmaxf(mx[j], __shfl_xor(mx[j], m, 64));
                mn[j] = fminf(mn[j], __shfl_xor(mn[j], m, 64));
            }
        }
        float smx = mx[0], smn = mn[0];
#pragma unroll
        for (int j = 1; j < 8; ++j) {
            smx = (l == j) ? mx[j] : smx;
            smn = (l == j) ? mn[j] : smn;
        }
        if (l < 8) {
            PTmax[half * DD + d0 + l] = smx;
            PTmin[half * DD + d0 + l] = smn;
        }
    }
    __syncthreads();   // also guards Hs: all conv1 reads done before epilogue writes

    {
        float rmax[8], rmin[8];
#pragma unroll
        for (int j = 0; j < 8; ++j) {
            rmax[j] = fmaxf(PTmax[d0 + j], PTmax[DD + d0 + j]);
            rmin[j] = fminf(PTmin[d0 + j], PTmin[DD + d0 + j]);
        }
#pragma unroll
        for (int cc = 0; cc < 2; ++cc) {
            const int n = (c0 + cc) * 64 + l;
            float h[8];
#pragma unroll
            for (int j = 0; j < 8; ++j) {
                float gv = ge1[d0 + j];
                float sv = ti[cc][j] + (gv >= 0.f ? rmax[j] : rmin[j]) + be1[d0 + j];
                h[j] = gv * fmaxf(sv, 0.f) + bte1[d0 + j];
            }
            float* o = Hs + (size_t)n * SROW + d0;
            *(float4*)(o)     = make_float4(h[0], h[1], h[2], h[3]);
            *(float4*)(o + 4) = make_float4(h[4], h[5], h[6], h[7]);
        }
    }
    __syncthreads();

    // ============ conv2: matvec + tj reduce ============
    {
        float tj[2][8];
#pragma unroll
        for (int cc = 0; cc < 2; ++cc)
#pragma unroll
            for (int j = 0; j < 8; ++j) { ti[cc][j] = 0.f; tj[cc][j] = 0.f; }
#pragma unroll
        for (int cc = 0; cc < 2; ++cc) {
            const float* hrow = Hs + (size_t)((c0 + cc) * 64 + l) * SROW;
#pragma unroll
            for (int k4 = 0; k4 < 16; ++k4) {
                float4 hv = *(const float4*)(hrow + k4 * 4);
                const float hk[4] = {hv.x, hv.y, hv.z, hv.w};
#pragma unroll
                for (int kk = 0; kk < 4; ++kk) {
                    const int k = k4 * 4 + kk;
                    const float* wi = We2 + k * DD + d0;
                    const float* wj = We2 + (DD + k) * DD + d0;
#pragma unroll
                    for (int j = 0; j < 8; ++j) {
                        ti[cc][j] = fmaf(hk[kk], wi[j], ti[cc][j]);
                        tj[cc][j] = fmaf(hk[kk], wj[j], tj[cc][j]);
                    }
                }
            }
        }
        float mx[8], mn[8];
#pragma unroll
        for (int j = 0; j < 8; ++j) {
            mx[j] = fmaxf(tj[0][j], tj[1][j]);
            mn[j] = fminf(tj[0][j], tj[1][j]);
        }
#pragma unroll
        for (int m = 1; m < 64; m <<= 1) {
#pragma unroll
            for (int j = 0; j < 8; ++j) {
                mx[j] = fmaxf(mx[j], __shfl_xor(mx[j], m, 64));
                mn[j] = fminf(mn[j], __shfl_xor(mn[j], m, 64));
            }
        }
        float smx = mx[0], smn = mn[0];
#pragma unroll
        for (int j = 1; j < 8; ++j) {
            smx = (l == j) ? mx[j] : smx;
            smn = (l == j) ? mn[j] : smn;
        }
        if (l < 8) {
            PTmax[half * DD + d0 + l] = smx;   // safe: conv1 partial reads all pre-barrier
            PTmin[half * DD + d0 + l] = smn;
        }
    }
    __syncthreads();

    // ============ conv2 epilogue + pooling partials ============
    {
        float rmax[8], rmin[8];
#pragma unroll
        for (int j = 0; j < 8; ++j) {
            rmax[j] = fmaxf(PTmax[d0 + j], PTmax[DD + d0 + j]);
            rmin[j] = fminf(PTmin[d0 + j], PTmin[DD + d0 + j]);
        }
        float sm[8], mxp[8];
#pragma unroll
        for (int j = 0; j < 8; ++j) { sm[j] = 0.f; mxp[j] = -FMAXV; }
#pragma unroll
        for (int cc = 0; cc < 2; ++cc) {
#pragma unroll
            for (int j = 0; j < 8; ++j) {
                float gv = ge2[d0 + j];
                float sv = ti[cc][j] + (gv >= 0.f ? rmax[j] : rmin[j]) + be2[d0 + j];
                float hv = gv * fmaxf(sv, 0.f) + bte2[d0 + j];
                sm[j] += hv;
                mxp[j] = fmaxf(mxp[j], hv);
            }
        }
#pragma unroll
        for (int m = 1; m < 64; m <<= 1) {
#pragma unroll
            for (int j = 0; j < 8; ++j) {
                sm[j] += __shfl_xor(sm[j], m, 64);
                mxp[j] = fmaxf(mxp[j], __shfl_xor(mxp[j], m, 64));
            }
        }
        float ssm = sm[0], smxp = mxp[0];
#pragma unroll
        for (int j = 1; j < 8; ++j) {
            ssm  = (l == j) ? sm[j]  : ssm;
            smxp = (l == j) ? mxp[j] : smxp;
        }
        if (l < 8) {
            PS[half * DD + d0 + l] = ssm;
            PM[half * DD + d0 + l] = smxp;
        }
    }
    __syncthreads();

    // ============ pooling finalize + head MLP ============
    const int t = threadIdx.x;
    if (t < DD) {
        xg[t] = (PS[t] + PS[DD + t]) * (1.f / 256.f);
    } else if (t < 2 * DD) {
        xg[t] = fmaxf(PM[t - DD], PM[t]);   // t-DD = dim, PM[half=0][d], PM[half=1][d]
    }
    __syncthreads();
    if (t < DD) {
        float a = bg1[t];
#pragma unroll
        for (int k = 0; k < 2 * DD; ++k) a = fmaf(xg[k], Wg1[k * DD + t], a);
        hid[t] = fmaxf(a, 0.f);
    }
    __syncthreads();
    if (t < 2) {
        float o = bg2[t];
#pragma unroll
        for (int j = 0; j < DD; ++j) o = fmaf(hid[j], Wg2[j * 2 + t], o);
        out[b * 2 + t] = o;
    }
}

extern "C" void kernel_launch(void* const* d_in, const int* in_sizes, int n_in,
                              void* d_out, int out_size, void* d_ws, size_t ws_size,
                              hipStream_t stream) {
    const float* x     = (const float*)d_in[0];
    const float* W1    = (const float*)d_in[1];
    const float* b1    = (const float*)d_in[2];
    const float* g1    = (const float*)d_in[3];
    const float* beta1 = (const float*)d_in[4];
    const float* We1   = (const float*)d_in[5];
    const float* be1   = (const float*)d_in[6];
    const float* ge1   = (const float*)d_in[7];
    const float* bte1  = (const float*)d_in[8];
    const float* We2   = (const float*)d_in[9];
    const float* be2   = (const float*)d_in[10];
    const float* ge2   = (const float*)d_in[11];
    const float* bte2  = (const float*)d_in[12];
    const float* Wg1   = (const float*)d_in[13];
    const float* bg1   = (const float*)d_in[14];
    const float* Wg2   = (const float*)d_in[15];
    const float* bg2   = (const float*)d_in[16];

    k_all<<<dim3(NB), dim3(1024), 0, stream>>>(
        x, W1, b1, g1, beta1,
        We1, be1, ge1, bte1,
        We2, be2, ge2, bte2,
        Wg1, bg1, Wg2, bg2, (float*)d_out);
}

// Round 4
// 130.769 us; speedup vs baseline: 2.0448x; 2.0448x over previous
//
#include <hip/hip_runtime.h>

#define NB 32
#define NN 256
#define DD 64
#define SROW 68          // LDS row stride in floats (17 float4) -> 2-way-max aliasing (free)
#define FMAXV 3.402823466e+38f

// R10: single dispatch, one block per batch (32 x 1024), all reductions
// intra-block. R9's structure was right but __launch_bounds__(1024) let the
// compiler target 8 waves/EU -> 64-VGPR cap -> massive scratch spills
// (WRITE_SIZE 12.4MB of spill traffic, 189us). Fixes:
//  - __launch_bounds__(1024, 4): 4 waves/EU = 1 block/CU -> 128-VGPR cap.
//  - 4-dims-per-wave layout (16 waves x 4 dims, all 256 nodes per wave,
//    4 nodes per lane): tj max/min and pooling reduce fully IN-REGISTER
//    (fold 4 nodes + one 64-lane butterfly; result identical in all lanes).
//    No LDS partials, 2 fewer barriers, ti[4][4]=16 persistent VGPRs.
// Window model (calibrated R8/R9): 1-dispatch fixed overhead ~78us; kernel
// VALU floor ~14us -> predict ~95-100us total.

__global__ __launch_bounds__(1024, 4) void k_all(
    const float* __restrict__ x,
    const float* __restrict__ W1,  const float* __restrict__ b1,
    const float* __restrict__ g1,  const float* __restrict__ beta1,
    const float* __restrict__ We1, const float* __restrict__ be1,
    const float* __restrict__ ge1, const float* __restrict__ bte1,
    const float* __restrict__ We2, const float* __restrict__ be2,
    const float* __restrict__ ge2, const float* __restrict__ bte2,
    const float* __restrict__ Wg1, const float* __restrict__ bg1,
    const float* __restrict__ Wg2, const float* __restrict__ bg2,
    float* __restrict__ out)
{
    __shared__ __align__(16) float Hs[NN * SROW];   // 69,632 B
    __shared__ float xg[2 * DD];
    __shared__ float hid[DD];

    const int b  = blockIdx.x;
    const int l  = threadIdx.x & 63;                                 // node lane
    const int w  = __builtin_amdgcn_readfirstlane(threadIdx.x >> 6); // wave 0..15 (SGPR)
    const int d0 = w * 4;                                            // wave's 4-dim slice

    // ================= layer 1: h1 -> Hs =================
#pragma unroll
    for (int cc = 0; cc < 4; ++cc) {
        const int n = cc * 64 + l;
        float4 xv = *(const float4*)(x + ((size_t)b * NN + n) * 4);
        float a[4];
#pragma unroll
        for (int j = 0; j < 4; ++j) a[j] = b1[d0 + j];
#pragma unroll
        for (int j = 0; j < 4; ++j) a[j] = fmaf(xv.x, W1[0 * DD + d0 + j], a[j]);
#pragma unroll
        for (int j = 0; j < 4; ++j) a[j] = fmaf(xv.y, W1[1 * DD + d0 + j], a[j]);
#pragma unroll
        for (int j = 0; j < 4; ++j) a[j] = fmaf(xv.z, W1[2 * DD + d0 + j], a[j]);
#pragma unroll
        for (int j = 0; j < 4; ++j) a[j] = fmaf(xv.w, W1[3 * DD + d0 + j], a[j]);
        float h[4];
#pragma unroll
        for (int j = 0; j < 4; ++j) h[j] = g1[d0 + j] * fmaxf(a[j], 0.f) + beta1[d0 + j];
        *(float4*)(Hs + (size_t)n * SROW + d0) = make_float4(h[0], h[1], h[2], h[3]);
    }
    __syncthreads();

    float ti[4][4];          // persistent per-conv accumulators (16 VGPRs)
    float rmax[4], rmin[4];  // in-register reduction results (same in all lanes)

    // ============ conv1: matvec + in-register tj reduce ============
    {
        float mx[4] = {-FMAXV, -FMAXV, -FMAXV, -FMAXV};
        float mn[4] = { FMAXV,  FMAXV,  FMAXV,  FMAXV};
#pragma unroll
        for (int cc = 0; cc < 4; ++cc) {
            float tj[4] = {0.f, 0.f, 0.f, 0.f};
#pragma unroll
            for (int j = 0; j < 4; ++j) ti[cc][j] = 0.f;
            const float* hrow = Hs + (size_t)(cc * 64 + l) * SROW;
#pragma unroll
            for (int k4 = 0; k4 < 16; ++k4) {
                float4 hv = *(const float4*)(hrow + k4 * 4);
                const float hk[4] = {hv.x, hv.y, hv.z, hv.w};
#pragma unroll
                for (int kk = 0; kk < 4; ++kk) {
                    const int k = k4 * 4 + kk;
                    const float* wi = We1 + k * DD + d0;          // wave-uniform -> s_load
                    const float* wj = We1 + (DD + k) * DD + d0;   // wave-uniform -> s_load
#pragma unroll
                    for (int j = 0; j < 4; ++j) {
                        ti[cc][j] = fmaf(hk[kk], wi[j], ti[cc][j]);
                        tj[j]     = fmaf(hk[kk], wj[j], tj[j]);
                    }
                }
            }
#pragma unroll
            for (int j = 0; j < 4; ++j) {
                mx[j] = fmaxf(mx[j], tj[j]);
                mn[j] = fminf(mn[j], tj[j]);
            }
        }
#pragma unroll
        for (int m = 1; m < 64; m <<= 1) {
#pragma unroll
            for (int j = 0; j < 4; ++j) {
                mx[j] = fmaxf(mx[j], __shfl_xor(mx[j], m, 64));
                mn[j] = fminf(mn[j], __shfl_xor(mn[j], m, 64));
            }
        }
#pragma unroll
        for (int j = 0; j < 4; ++j) { rmax[j] = mx[j]; rmin[j] = mn[j]; }
    }
    __syncthreads();   // all conv1 Hs reads complete before epilogue overwrites

    // ============ conv1 epilogue -> Hs (monotone bn o max) ============
#pragma unroll
    for (int cc = 0; cc < 4; ++cc) {
        const int n = cc * 64 + l;
        float h[4];
#pragma unroll
        for (int j = 0; j < 4; ++j) {
            float gv = ge1[d0 + j];
            float sv = ti[cc][j] + (gv >= 0.f ? rmax[j] : rmin[j]) + be1[d0 + j];
            h[j] = gv * fmaxf(sv, 0.f) + bte1[d0 + j];
        }
        *(float4*)(Hs + (size_t)n * SROW + d0) = make_float4(h[0], h[1], h[2], h[3]);
    }
    __syncthreads();

    // ============ conv2: matvec + in-register tj reduce ============
    {
        float mx[4] = {-FMAXV, -FMAXV, -FMAXV, -FMAXV};
        float mn[4] = { FMAXV,  FMAXV,  FMAXV,  FMAXV};
#pragma unroll
        for (int cc = 0; cc < 4; ++cc) {
            float tj[4] = {0.f, 0.f, 0.f, 0.f};
#pragma unroll
            for (int j = 0; j < 4; ++j) ti[cc][j] = 0.f;
            const float* hrow = Hs + (size_t)(cc * 64 + l) * SROW;
#pragma unroll
            for (int k4 = 0; k4 < 16; ++k4) {
                float4 hv = *(const float4*)(hrow + k4 * 4);
                const float hk[4] = {hv.x, hv.y, hv.z, hv.w};
#pragma unroll
                for (int kk = 0; kk < 4; ++kk) {
                    const int k = k4 * 4 + kk;
                    const float* wi = We2 + k * DD + d0;
                    const float* wj = We2 + (DD + k) * DD + d0;
#pragma unroll
                    for (int j = 0; j < 4; ++j) {
                        ti[cc][j] = fmaf(hk[kk], wi[j], ti[cc][j]);
                        tj[j]     = fmaf(hk[kk], wj[j], tj[j]);
                    }
                }
            }
#pragma unroll
            for (int j = 0; j < 4; ++j) {
                mx[j] = fmaxf(mx[j], tj[j]);
                mn[j] = fminf(mn[j], tj[j]);
            }
        }
#pragma unroll
        for (int m = 1; m < 64; m <<= 1) {
#pragma unroll
            for (int j = 0; j < 4; ++j) {
                mx[j] = fmaxf(mx[j], __shfl_xor(mx[j], m, 64));
                mn[j] = fminf(mn[j], __shfl_xor(mn[j], m, 64));
            }
        }
#pragma unroll
        for (int j = 0; j < 4; ++j) { rmax[j] = mx[j]; rmin[j] = mn[j]; }
    }
    // no barrier needed: pooling below touches only registers + xg

    // ============ conv2 epilogue + pooling (in-register) ============
    {
        float sm[4]  = {0.f, 0.f, 0.f, 0.f};
        float mxp[4] = {-FMAXV, -FMAXV, -FMAXV, -FMAXV};
#pragma unroll
        for (int cc = 0; cc < 4; ++cc) {
#pragma unroll
            for (int j = 0; j < 4; ++j) {
                float gv = ge2[d0 + j];
                float sv = ti[cc][j] + (gv >= 0.f ? rmax[j] : rmin[j]) + be2[d0 + j];
                float hv = gv * fmaxf(sv, 0.f) + bte2[d0 + j];
                sm[j]  += hv;
                mxp[j]  = fmaxf(mxp[j], hv);
            }
        }
#pragma unroll
        for (int m = 1; m < 64; m <<= 1) {
#pragma unroll
            for (int j = 0; j < 4; ++j) {
                sm[j]  += __shfl_xor(sm[j], m, 64);
                mxp[j]  = fmaxf(mxp[j], __shfl_xor(mxp[j], m, 64));
            }
        }
        float ssm = sm[0], smxp = mxp[0];
#pragma unroll
        for (int j = 1; j < 4; ++j) {
            ssm  = (l == j) ? sm[j]  : ssm;
            smxp = (l == j) ? mxp[j] : smxp;
        }
        if (l < 4) {
            xg[d0 + l]      = ssm * (1.f / 256.f);
            xg[DD + d0 + l] = smxp;
        }
    }
    __syncthreads();

    // ============ head MLP ============
    const int t = threadIdx.x;
    if (t < DD) {
        float a = bg1[t];
#pragma unroll
        for (int k = 0; k < 2 * DD; ++k) a = fmaf(xg[k], Wg1[k * DD + t], a);
        hid[t] = fmaxf(a, 0.f);
    }
    __syncthreads();
    if (t < 2) {
        float o = bg2[t];
#pragma unroll
        for (int j = 0; j < DD; ++j) o = fmaf(hid[j], Wg2[j * 2 + t], o);
        out[b * 2 + t] = o;
    }
}

extern "C" void kernel_launch(void* const* d_in, const int* in_sizes, int n_in,
                              void* d_out, int out_size, void* d_ws, size_t ws_size,
                              hipStream_t stream) {
    const float* x     = (const float*)d_in[0];
    const float* W1    = (const float*)d_in[1];
    const float* b1    = (const float*)d_in[2];
    const float* g1    = (const float*)d_in[3];
    const float* beta1 = (const float*)d_in[4];
    const float* We1   = (const float*)d_in[5];
    const float* be1   = (const float*)d_in[6];
    const float* ge1   = (const float*)d_in[7];
    const float* bte1  = (const float*)d_in[8];
    const float* We2   = (const float*)d_in[9];
    const float* be2   = (const float*)d_in[10];
    const float* ge2   = (const float*)d_in[11];
    const float* bte2  = (const float*)d_in[12];
    const float* Wg1   = (const float*)d_in[13];
    const float* bg1   = (const float*)d_in[14];
    const float* Wg2   = (const float*)d_in[15];
    const float* bg2   = (const float*)d_in[16];

    k_all<<<dim3(NB), dim3(1024), 0, stream>>>(
        x, W1, b1, g1, beta1,
        We1, be1, ge1, bte1,
        We2, be2, ge2, bte2,
        Wg1, bg1, Wg2, bg2, (float*)d_out);
}